// Round 9
// baseline (99.239 us; speedup 1.0000x reference)
//
#include <hip/hip_runtime.h>
#include <math.h>

#define CCH 64
#define HW 441
#define HWP 448
#define NT 28
#define NB2 25
#define PANEL (HWP * CCH)   // 28672 halves per panel
#define NI 4                // i-tiles per block (7 groups x 4 = 28)

typedef _Float16 half8 __attribute__((ext_vector_type(8)));
typedef __fp16 h2 __attribute__((ext_vector_type(2)));
typedef float f32x4 __attribute__((ext_vector_type(4)));

// ---- kernel 1: fold mask + 1/norm into f16 descriptors, write in MFMA
// fragment order: panel[tile][kfrag][lane][8] where lane = quad*16 + m,
// row i = tile*16 + m, col c = kfrag*32 + quad*8 + e. Also zeroes d_out.
__global__ __launch_bounds__(64) void normalize_frag_kernel(
        const float* __restrict__ x1, const float* __restrict__ m1,
        const float* __restrict__ x2, const float* __restrict__ m2,
        _Float16* __restrict__ qh, _Float16* __restrict__ sh,
        float* __restrict__ out, int nout, int n1rows, int nrows) {
    int idx = blockIdx.x * blockDim.x + threadIdx.x;
    if (idx < nout) out[idx] = 0.f;
    if (idx >= nrows) return;
    const float* x; const float* mk; _Float16* outp; int rb;
    if (idx < n1rows) { x = x1; mk = m1; outp = qh; rb = idx; }
    else             { x = x2; mk = m2; outp = sh; rb = idx - n1rows; }
    int b = rb / HWP, i = rb - b * HWP;
    float vals[CCH];
    if (i < HW) {
        const float* xb = x + (size_t)b * CCH * HW + i;
        float ss = 0.f;
#pragma unroll
        for (int c = 0; c < CCH; ++c) { float v = xb[c * HW]; vals[c] = v; ss += v * v; }
        float scale = mk[b * HW + i] * rsqrtf(ss);
#pragma unroll
        for (int c = 0; c < CCH; ++c) vals[c] *= scale;
    } else {
#pragma unroll
        for (int c = 0; c < CCH; ++c) vals[c] = 0.f;
    }
    _Float16* pb = outp + (size_t)b * PANEL + (i >> 4) * 1024 + (i & 15) * 8;
#pragma unroll
    for (int f = 0; f < 2; ++f) {
#pragma unroll
        for (int qd = 0; qd < 4; ++qd) {
            half8 h;
#pragma unroll
            for (int e = 0; e < 8; ++e) h[e] = (_Float16)vals[f * 32 + qd * 8 + e];
            *(half8*)(pb + f * 512 + qd * 128) = h;
        }
    }
}

static __device__ __forceinline__ h2 hmax2(h2 a, h2 b) {
    return __builtin_elementwise_max(a, b);
}
static __device__ __forceinline__ h2 hmin2(h2 a, h2 b) {
    return __builtin_elementwise_min(a, b);
}

// packed top-3 insert: lo/hi halves are two independent triples. 5 packed ops.
#define PK_INSERT(v, p0, p1, p2)           \
    do {                                   \
        h2 _m = hmax2(p0, v);              \
        h2 _c = hmin2(p0, v);              \
        p0 = _m;                           \
        _m = hmax2(p1, _c);                \
        _c = hmin2(p1, _c);                \
        p1 = _m;                           \
        p2 = hmax2(p2, _c);                \
    } while (0)

// merge two desc-sorted f32 triples -> top3 of union in (t0,t1,t2)
#define MERGE3(t0, t1, t2, b0, b1, b2)            \
    do {                                          \
        float _m0 = fmaxf(t0, b0);                \
        float _n0 = fminf(t0, b0);                \
        float _m1 = fmaxf(t1, b1);                \
        float _t2 = fmaxf(t2, b2);                \
        t0 = _m0;                                 \
        t1 = fmaxf(_n0, _m1);                     \
        t2 = fmaxf(fminf(_n0, _m1), _t2);         \
    } while (0)

// process one j-tile (frags a0,a1) against NI i-tiles
template <bool MASK>
__device__ __forceinline__ void tile_compute(half8 a0, half8 a1,
                                             const half8 (&bf0)[NI], const half8 (&bf1)[NI],
                                             h2 (&p0)[NI], h2 (&p1)[NI], h2 (&p2)[NI],
                                             int quad) {
    const f32x4 FZ = {0.f, 0.f, 0.f, 0.f};
    const float NEG = -1e30f;
#pragma unroll
    for (int t = 0; t < NI; ++t) {
        f32x4 z = __builtin_amdgcn_mfma_f32_16x16x32_f16(a0, bf0[t], FZ, 0, 0, 0);
        z = __builtin_amdgcn_mfma_f32_16x16x32_f16(a1, bf1[t], z, 0, 0, 0);
        if (MASK) {
#pragma unroll
            for (int r = 0; r < 4; ++r)
                if (quad * 4 + r >= 9) z[r] = NEG;
        }
        h2 c02 = __builtin_amdgcn_cvt_pkrtz(z[0], z[2]);
        h2 c13 = __builtin_amdgcn_cvt_pkrtz(z[1], z[3]);
        PK_INSERT(c02, p0[t], p1[t], p2[t]);
        PK_INSERT(c13, p0[t], p1[t], p2[t]);
    }
}

// Sweep 14 j-tiles (tiles jt0..jt0+13; last one masked if MASKED) for NI
// i-tiles. 2-tile unrolled loop with depth-2-pair register prefetch: 4
// independent 16B loads in flight while computing 2 tiles (~460 cyc work).
// Outputs per-column desc-sorted triples (column = tile t, row m = lane&15).
template <bool MASKED>
__device__ __forceinline__ void do_sweep(const _Float16* __restrict__ qtiles,
                                         const _Float16* __restrict__ spanel,
                                         int jt0, int lane, int quad,
                                         float (&t0)[NI], float (&t1)[NI], float (&t2)[NI]) {
    const h2 NEGH = {(__fp16)-65504.f, (__fp16)-65504.f};
    half8 bf0[NI], bf1[NI];
#pragma unroll
    for (int t = 0; t < NI; ++t) {
        const _Float16* qp = qtiles + t * 1024 + lane * 8;
        bf0[t] = *(const half8*)qp;
        bf1[t] = *(const half8*)(qp + 512);
    }
    h2 p0[NI], p1[NI], p2[NI];
#pragma unroll
    for (int t = 0; t < NI; ++t) { p0[t] = NEGH; p1[t] = NEGH; p2[t] = NEGH; }

    const _Float16* sp = spanel + (size_t)jt0 * 1024 + lane * 8;
    // tiles local 0..13
    half8 c0a = *(const half8*)(sp);                  // tile 0
    half8 c0b = *(const half8*)(sp + 512);
    half8 c1a = *(const half8*)(sp + 1024);           // tile 1
    half8 c1b = *(const half8*)(sp + 1024 + 512);
    half8 n0a = *(const half8*)(sp + 2048);           // tile 2
    half8 n0b = *(const half8*)(sp + 2048 + 512);
    half8 n1a = *(const half8*)(sp + 3072);           // tile 3
    half8 n1b = *(const half8*)(sp + 3072 + 512);

    for (int it = 0; it < 6; ++it) {
        int pf0 = 2 * it + 4; if (pf0 > 13) pf0 = 13;
        int pf1 = 2 * it + 5; if (pf1 > 13) pf1 = 13;
        const _Float16* pp0 = sp + (size_t)pf0 * 1024;
        const _Float16* pp1 = sp + (size_t)pf1 * 1024;
        half8 f0a = *(const half8*)pp0;
        half8 f0b = *(const half8*)(pp0 + 512);
        half8 f1a = *(const half8*)pp1;
        half8 f1b = *(const half8*)(pp1 + 512);

        tile_compute<false>(c0a, c0b, bf0, bf1, p0, p1, p2, quad);
        tile_compute<false>(c1a, c1b, bf0, bf1, p0, p1, p2, quad);

        c0a = n0a; c0b = n0b; c1a = n1a; c1b = n1b;
        n0a = f0a; n0b = f0b; n1a = f1a; n1b = f1b;
    }
    // final pair: tiles 12,13 (in c-regs); tile 13 masked if MASKED
    tile_compute<false>(c0a, c0b, bf0, bf1, p0, p1, p2, quad);
    tile_compute<MASKED>(c1a, c1b, bf0, bf1, p0, p1, p2, quad);

#pragma unroll
    for (int t = 0; t < NI; ++t) {
        // lo/hi stream merge in f32
        float a0 = (float)p0[t][0], a1 = (float)p1[t][0], a2 = (float)p2[t][0];
        float b0 = (float)p0[t][1], b1 = (float)p1[t][1], b2 = (float)p2[t][1];
        MERGE3(a0, a1, a2, b0, b1, b2);
        // cross-quad merges: each column lives in 4 lanes (quads)
        b0 = __shfl_xor(a0, 16); b1 = __shfl_xor(a1, 16); b2 = __shfl_xor(a2, 16);
        MERGE3(a0, a1, a2, b0, b1, b2);
        b0 = __shfl_xor(a0, 32); b1 = __shfl_xor(a1, 32); b2 = __shfl_xor(a2, 32);
        MERGE3(a0, a1, a2, b0, b1, b2);
        t0[t] = a0; t1[t] = a1; t2[t] = a2;
    }
}

// ---- kernel 2: 7 blocks per (a,b) pair (4 i-tiles each), 2 waves = 2 j-halves.
// Cross-half triple merge via LDS, then one atomicAdd per block.
__global__ __launch_bounds__(128) void sim_topk_mfma(const _Float16* __restrict__ qh,
                                                     const _Float16* __restrict__ sh,
                                                     float* __restrict__ out) {
    __shared__ float s_tri[2][NI][16][3];   // 1536 B
    int blk = blockIdx.x;
    int pair = blk / 7, g = blk - pair * 7;
    int a = pair / NB2, b = pair - a * NB2;
    int tid = threadIdx.x, wave = tid >> 6, lane = tid & 63;
    int m = lane & 15, quad = lane >> 4;
    const _Float16* qtiles = qh + (size_t)a * PANEL + (size_t)g * NI * 1024;
    const _Float16* spanel = sh + (size_t)b * PANEL;

    float t0[NI], t1[NI], t2[NI];
    if (wave == 0)
        do_sweep<false>(qtiles, spanel, 0, lane, quad, t0, t1, t2);
    else
        do_sweep<true>(qtiles, spanel, 14, lane, quad, t0, t1, t2);

    if (quad == 0) {
#pragma unroll
        for (int t = 0; t < NI; ++t) {
            s_tri[wave][t][m][0] = t0[t];
            s_tri[wave][t][m][1] = t1[t];
            s_tri[wave][t][m][2] = t2[t];
        }
    }
    __syncthreads();

    if (wave == 0) {
        // 64 lanes <-> 64 columns: t = lane>>4, m = lane&15
        int t = quad;
        float a0 = s_tri[0][t][m][0], a1 = s_tri[0][t][m][1], a2 = s_tri[0][t][m][2];
        float b0 = s_tri[1][t][m][0], b1 = s_tri[1][t][m][1], b2 = s_tri[1][t][m][2];
        MERGE3(a0, a1, a2, b0, b1, b2);
        float r = a0 + a1 + a2;
#pragma unroll
        for (int off = 32; off > 0; off >>= 1) r += __shfl_down(r, off);
        if (lane == 0) atomicAdd(&out[pair], r);
    }
}

extern "C" void kernel_launch(void* const* d_in, const int* in_sizes, int n_in,
                              void* d_out, int out_size, void* d_ws, size_t ws_size,
                              hipStream_t stream) {
    const float* x1 = (const float*)d_in[0];
    const float* x2 = (const float*)d_in[1];
    const float* m1 = (const float*)d_in[2];
    const float* m2 = (const float*)d_in[3];
    float* out = (float*)d_out;

    int B1 = in_sizes[0] / (CCH * HW);
    int B2 = in_sizes[1] / (CCH * HW);

    _Float16* qh = (_Float16*)d_ws;
    _Float16* sh = qh + (size_t)B1 * PANEL;

    int n1 = B1 * HWP, ntot = (B1 + B2) * HWP;
    normalize_frag_kernel<<<(ntot + 63) / 64, 64, 0, stream>>>(
        x1, m1, x2, m2, qh, sh, out, B1 * B2, n1, ntot);
    sim_topk_mfma<<<B1 * B2 * 7, 128, 0, stream>>>(qh, sh, out);
}